// Round 2
// baseline (2780.300 us; speedup 1.0000x reference)
//
#include <hip/hip_runtime.h>
#include <math.h>

#define DIM   256
#define KNN   16
#define NPTS  2048
#define NB    8
#define TOTPTS (NB * NPTS)   // 16384

// ------------------------------------------------------------------
// Kernel 1: kNN (top-16 smallest squared distances, self included)
// one block per query point; 256 threads; each thread holds 8 candidates
// ------------------------------------------------------------------
__global__ __launch_bounds__(256, 4)
void knn_kernel(const float* __restrict__ pos, int* __restrict__ knn_out) {
    const int pt = blockIdx.x;
    const int b  = pt >> 11;          // / 2048
    const int n  = pt & (NPTS - 1);
    const int t  = threadIdx.x;
    const float* __restrict__ posb = pos + (size_t)b * NPTS * 3;

    const float qx = posb[n * 3 + 0], qy = posb[n * 3 + 1], qz = posb[n * 3 + 2];
    const float sqn = __fadd_rn(__fadd_rn(__fmul_rn(qx, qx), __fmul_rn(qy, qy)),
                                __fmul_rn(qz, qz));
    float d[8];
    #pragma unroll
    for (int i = 0; i < 8; ++i) {
        const int m = t + (i << 8);
        const float mx = posb[m * 3 + 0], my = posb[m * 3 + 1], mz = posb[m * 3 + 2];
        const float sqm = __fadd_rn(__fadd_rn(__fmul_rn(mx, mx), __fmul_rn(my, my)),
                                    __fmul_rn(mz, mz));
        const float dot = __fadd_rn(__fadd_rn(__fmul_rn(qx, mx), __fmul_rn(qy, my)),
                                    __fmul_rn(qz, mz));
        d[i] = __fsub_rn(__fadd_rn(sqn, sqm), __fmul_rn(2.0f, dot));
    }

    __shared__ float sd[4];
    __shared__ int   sm[4];
    __shared__ int   swin;
    unsigned mask = 0;

    for (int r = 0; r < KNN; ++r) {
        float bd = 1e30f;
        int   bm = 0x7fffffff;
        #pragma unroll
        for (int i = 0; i < 8; ++i) {
            if (!((mask >> i) & 1u)) {
                const int m = t + (i << 8);
                if (d[i] < bd || (d[i] == bd && m < bm)) { bd = d[i]; bm = m; }
            }
        }
        #pragma unroll
        for (int off = 32; off >= 1; off >>= 1) {
            const float od = __shfl_xor(bd, off);
            const int   om = __shfl_xor(bm, off);
            if (od < bd || (od == bd && om < bm)) { bd = od; bm = om; }
        }
        const int w = t >> 6;
        if ((t & 63) == 0) { sd[w] = bd; sm[w] = bm; }
        __syncthreads();
        if (t == 0) {
            float fd = sd[0]; int fm = sm[0];
            #pragma unroll
            for (int w2 = 1; w2 < 4; ++w2)
                if (sd[w2] < fd || (sd[w2] == fd && sm[w2] < fm)) { fd = sd[w2]; fm = sm[w2]; }
            swin = fm;
            knn_out[(size_t)pt * KNN + r] = fm;
        }
        __syncthreads();
        const int win = swin;
        if ((win & 255) == t) mask |= 1u << (win >> 8);
        __syncthreads();   // protect swin/sd/sm before next round's writes
    }
}

// ------------------------------------------------------------------
// Kernel 2: q/k/v projections  O = X @ W^T  (M=16384, N=256, K=256) x3
// 64x64 tile per block, 256 threads, 4x4 micro-tile per thread
// ------------------------------------------------------------------
#define TK 32
#define LPAD 68   // 68*4 = 272 bytes row stride, 16B aligned

__global__ __launch_bounds__(256, 2)
void qkv_gemm(const float* __restrict__ X,
              const float* __restrict__ Wq, const float* __restrict__ Wk,
              const float* __restrict__ Wv,
              float* __restrict__ Q, float* __restrict__ Kf, float* __restrict__ Vf) {
    __shared__ float Xt[TK][LPAD];
    __shared__ float Wt[3][TK][LPAD];
    const int t  = threadIdx.x;
    const int m0 = blockIdx.x * 64;
    const int n0 = blockIdx.y * 64;
    const int tm = t >> 4;      // 0..15
    const int tn = t & 15;      // 0..15

    float acc[3][4][4] = {};
    const float* __restrict__ Ws[3] = {Wq, Wk, Wv};

    for (int kb = 0; kb < DIM; kb += TK) {
        const int r  = t >> 3;          // 0..31
        const int kq = (t & 7) << 2;    // 0,4,...,28
        #pragma unroll
        for (int h = 0; h < 2; ++h) {
            const float4 v = *(const float4*)&X[(size_t)(m0 + r + 32 * h) * DIM + kb + kq];
            Xt[kq + 0][r + 32 * h] = v.x;
            Xt[kq + 1][r + 32 * h] = v.y;
            Xt[kq + 2][r + 32 * h] = v.z;
            Xt[kq + 3][r + 32 * h] = v.w;
        }
        #pragma unroll
        for (int s = 0; s < 3; ++s) {
            #pragma unroll
            for (int h = 0; h < 2; ++h) {
                const float4 v = *(const float4*)&Ws[s][(size_t)(n0 + r + 32 * h) * DIM + kb + kq];
                Wt[s][kq + 0][r + 32 * h] = v.x;
                Wt[s][kq + 1][r + 32 * h] = v.y;
                Wt[s][kq + 2][r + 32 * h] = v.z;
                Wt[s][kq + 3][r + 32 * h] = v.w;
            }
        }
        __syncthreads();
        #pragma unroll
        for (int k = 0; k < TK; ++k) {
            const float4 a4 = *(const float4*)&Xt[k][tm << 2];
            const float a[4] = {a4.x, a4.y, a4.z, a4.w};
            #pragma unroll
            for (int s = 0; s < 3; ++s) {
                const float4 b4 = *(const float4*)&Wt[s][k][tn << 2];
                const float bb[4] = {b4.x, b4.y, b4.z, b4.w};
                #pragma unroll
                for (int i = 0; i < 4; ++i)
                    #pragma unroll
                    for (int j = 0; j < 4; ++j)
                        acc[s][i][j] = fmaf(a[i], bb[j], acc[s][i][j]);
            }
        }
        __syncthreads();
    }

    float* __restrict__ Os[3] = {Q, Kf, Vf};
    #pragma unroll
    for (int s = 0; s < 3; ++s)
        #pragma unroll
        for (int i = 0; i < 4; ++i) {
            const size_t row = (size_t)(m0 + (tm << 2) + i);
            float4 v; v.x = acc[s][i][0]; v.y = acc[s][i][1]; v.z = acc[s][i][2]; v.w = acc[s][i][3];
            *(float4*)&Os[s][row * DIM + n0 + (tn << 2)] = v;
        }
}

// ------------------------------------------------------------------
// Kernel 3: fused per-point transformer
// 1 wave = 1 point; 4 waves/block. Lane owns columns {lane, lane+64, +128, +192}.
// LDS: 16x256 f32 stage buffer per wave.
// ------------------------------------------------------------------
#define FMA4(acc, a4, w4) \
    acc = fmaf((a4).w, (w4).w, fmaf((a4).z, (w4).z, fmaf((a4).y, (w4).y, fmaf((a4).x, (w4).x, (acc)))))

__device__ __forceinline__ void wave_gemm(const float (*__restrict__ Aw)[DIM],
                                          const float* __restrict__ W,
                                          int lane, float acc[KNN][4]) {
    const float* __restrict__ w0p = W + (size_t)(lane)       * DIM;
    const float* __restrict__ w1p = W + (size_t)(lane + 64)  * DIM;
    const float* __restrict__ w2p = W + (size_t)(lane + 128) * DIM;
    const float* __restrict__ w3p = W + (size_t)(lane + 192) * DIM;
    for (int d4 = 0; d4 < DIM / 4; ++d4) {
        const int o = d4 << 2;
        const float4 w0 = *(const float4*)(w0p + o);
        const float4 w1 = *(const float4*)(w1p + o);
        const float4 w2 = *(const float4*)(w2p + o);
        const float4 w3 = *(const float4*)(w3p + o);
        #pragma unroll
        for (int k = 0; k < KNN; ++k) {
            const float4 a4 = *(const float4*)(Aw[k] + o);
            FMA4(acc[k][0], a4, w0);
            FMA4(acc[k][1], a4, w1);
            FMA4(acc[k][2], a4, w2);
            FMA4(acc[k][3], a4, w3);
        }
    }
}

__global__ __launch_bounds__(256, 2)
void fused_attn(const float* __restrict__ x, const float* __restrict__ pos,
                const int* __restrict__ knn,
                const float* __restrict__ q, const float* __restrict__ kf,
                const float* __restrict__ vf,
                const float* __restrict__ pm_w1, const float* __restrict__ pm_g1,
                const float* __restrict__ pm_b1, const float* __restrict__ pm_m1,
                const float* __restrict__ pm_v1, const float* __restrict__ pm_w2,
                const float* __restrict__ am_w1, const float* __restrict__ am_g1,
                const float* __restrict__ am_b1, const float* __restrict__ am_m1,
                const float* __restrict__ am_v1, const float* __restrict__ am_w2,
                const float* __restrict__ Wf, const float* __restrict__ bfin,
                float* __restrict__ out) {
    __shared__ float A[4][KNN][DIM];   // 64 KB
    const int t    = threadIdx.x;
    const int w    = t >> 6;
    const int lane = t & 63;
    const int pt   = (blockIdx.x << 2) | w;
    const int b    = pt >> 11;
    const int n    = pt & (NPTS - 1);
    float (*__restrict__ Aw)[DIM] = A[w];

    // wave-uniform neighbor indices -> SGPRs
    int nb[KNN];
    #pragma unroll
    for (int k = 0; k < KNN; ++k)
        nb[k] = __builtin_amdgcn_readfirstlane(knn[(size_t)pt * KNN + k]);

    const float* __restrict__ posb = pos + (size_t)b * NPTS * 3;
    const float px = posb[n * 3 + 0], py = posb[n * 3 + 1], pz = posb[n * 3 + 2];

    // ---- stage 1: pe1 = relu(bn(rel @ pm_w1^T)) -> LDS ----
    {
        float w1c[4][3], sc[4], bs[4], mn[4];
        #pragma unroll
        for (int ci = 0; ci < 4; ++ci) {
            const int c = lane + (ci << 6);
            w1c[ci][0] = pm_w1[c * 3 + 0];
            w1c[ci][1] = pm_w1[c * 3 + 1];
            w1c[ci][2] = pm_w1[c * 3 + 2];
            sc[ci] = pm_g1[c] * rsqrtf(pm_v1[c] + 1e-5f);
            bs[ci] = pm_b1[c];
            mn[ci] = pm_m1[c];
        }
        for (int k = 0; k < KNN; ++k) {
            const int j = nb[k];
            const float rx = px - posb[j * 3 + 0];
            const float ry = py - posb[j * 3 + 1];
            const float rz = pz - posb[j * 3 + 2];
            #pragma unroll
            for (int ci = 0; ci < 4; ++ci) {
                float h = fmaf(rz, w1c[ci][2], fmaf(ry, w1c[ci][1], rx * w1c[ci][0]));
                h = fmaf(h - mn[ci], sc[ci], bs[ci]);
                Aw[k][lane + (ci << 6)] = fmaxf(h, 0.0f);
            }
        }
    }
    __syncthreads();

    // ---- stage 2: pe = pe1 @ pm_w2^T -> registers (kept to the end) ----
    float pe[KNN][4] = {};
    wave_gemm(Aw, pm_w2, lane, pe);
    __syncthreads();

    // ---- stage 3: a0 = q - k_gather + pe -> LDS ----
    {
        const float* __restrict__ qrow = q + (size_t)pt * DIM;
        float qc[4];
        #pragma unroll
        for (int ci = 0; ci < 4; ++ci) qc[ci] = qrow[lane + (ci << 6)];
        for (int k = 0; k < KNN; ++k) {
            const float* __restrict__ krow = kf + (size_t)(b * NPTS + nb[k]) * DIM;
            #pragma unroll
            for (int ci = 0; ci < 4; ++ci) {
                const int c = lane + (ci << 6);
                Aw[k][c] = qc[ci] - krow[c] + pe[k][ci];
            }
        }
    }
    __syncthreads();

    // ---- stage 4: a1 = relu(bn(a0 @ am_w1^T)) -> LDS ----
    float acc[KNN][4] = {};
    wave_gemm(Aw, am_w1, lane, acc);
    {
        float sc[4], bs[4], mn[4];
        #pragma unroll
        for (int ci = 0; ci < 4; ++ci) {
            const int c = lane + (ci << 6);
            sc[ci] = am_g1[c] * rsqrtf(am_v1[c] + 1e-5f);
            bs[ci] = am_b1[c];
            mn[ci] = am_m1[c];
        }
        __syncthreads();   // all reads of a0 done before overwrite
        for (int k = 0; k < KNN; ++k)
            #pragma unroll
            for (int ci = 0; ci < 4; ++ci) {
                float h = fmaf(acc[k][ci] - mn[ci], sc[ci], bs[ci]);
                Aw[k][lane + (ci << 6)] = fmaxf(h, 0.0f);
            }
    }
    __syncthreads();

    // ---- stage 5: a2 = a1 @ am_w2^T -> registers ----
    #pragma unroll
    for (int k = 0; k < KNN; ++k)
        #pragma unroll
        for (int ci = 0; ci < 4; ++ci) acc[k][ci] = 0.0f;
    wave_gemm(Aw, am_w2, lane, acc);

    // ---- stage 6: softmax over K (thread-local per column) ----
    #pragma unroll
    for (int ci = 0; ci < 4; ++ci) {
        float mx = -1e30f;
        #pragma unroll
        for (int k = 0; k < KNN; ++k) {
            acc[k][ci] *= 0.0625f;            // / sqrt(256)
            mx = fmaxf(mx, acc[k][ci]);
        }
        float s = 0.0f;
        #pragma unroll
        for (int k = 0; k < KNN; ++k) {
            acc[k][ci] = __expf(acc[k][ci] - mx);
            s += acc[k][ci];
        }
        #pragma unroll
        for (int k = 0; k < KNN; ++k) acc[k][ci] /= s;
    }

    // ---- stage 7: agg = sum_k attn * (v_gather + pe) ----
    float agg[4] = {};
    for (int k = 0; k < KNN; ++k) {
        const float* __restrict__ vrow = vf + (size_t)(b * NPTS + nb[k]) * DIM;
        #pragma unroll
        for (int ci = 0; ci < 4; ++ci) {
            const int c = lane + (ci << 6);
            agg[ci] = fmaf(acc[k][ci], vrow[c] + pe[k][ci], agg[ci]);
        }
    }
    __syncthreads();   // a1 reads done; reuse LDS for agg exchange
    #pragma unroll
    for (int ci = 0; ci < 4; ++ci) Aw[0][lane + (ci << 6)] = agg[ci];
    __syncthreads();

    // ---- stage 8: out = agg @ Wf^T + bf + x ----
    #pragma unroll
    for (int ci = 0; ci < 4; ++ci) {
        const int c = lane + (ci << 6);
        const float* __restrict__ wfr = Wf + (size_t)c * DIM;
        float o = 0.0f;
        for (int d4 = 0; d4 < DIM / 4; ++d4) {
            const int of = d4 << 2;
            const float4 a4 = *(const float4*)(&Aw[0][0] + of);
            const float4 w4 = *(const float4*)(wfr + of);
            FMA4(o, a4, w4);
        }
        out[(size_t)pt * DIM + c] = o + bfin[c] + x[(size_t)pt * DIM + c];
    }
}

// ------------------------------------------------------------------
extern "C" void kernel_launch(void* const* d_in, const int* in_sizes, int n_in,
                              void* d_out, int out_size, void* d_ws, size_t ws_size,
                              hipStream_t stream) {
    const float* x     = (const float*)d_in[0];
    const float* pos   = (const float*)d_in[1];
    const float* Wq    = (const float*)d_in[2];
    const float* Wk    = (const float*)d_in[3];
    const float* Wv    = (const float*)d_in[4];
    const float* pm_w1 = (const float*)d_in[5];
    const float* pm_g1 = (const float*)d_in[6];
    const float* pm_b1 = (const float*)d_in[7];
    const float* pm_m1 = (const float*)d_in[8];
    const float* pm_v1 = (const float*)d_in[9];
    const float* pm_w2 = (const float*)d_in[10];
    const float* am_w1 = (const float*)d_in[11];
    const float* am_g1 = (const float*)d_in[12];
    const float* am_b1 = (const float*)d_in[13];
    const float* am_m1 = (const float*)d_in[14];
    const float* am_v1 = (const float*)d_in[15];
    const float* am_w2 = (const float*)d_in[16];
    const float* Wf    = (const float*)d_in[17];
    const float* bfin  = (const float*)d_in[18];
    float* out = (float*)d_out;

    char* ws = (char*)d_ws;
    int*   knn_idx = (int*)ws;                              // 1 MB
    float* qf = (float*)(ws + (1u << 20));                  // 16 MB
    float* kf = (float*)(ws + (1u << 20) + (16u << 20));    // 16 MB
    float* vf = (float*)(ws + (1u << 20) + (32u << 20));    // 16 MB

    knn_kernel<<<TOTPTS, 256, 0, stream>>>(pos, knn_idx);
    qkv_gemm<<<dim3(TOTPTS / 64, DIM / 64), 256, 0, stream>>>(x, Wq, Wk, Wv, qf, kf, vf);
    fused_attn<<<TOTPTS / 4, 256, 0, stream>>>(x, pos, knn_idx, qf, kf, vf,
                                               pm_w1, pm_g1, pm_b1, pm_m1, pm_v1, pm_w2,
                                               am_w1, am_g1, am_b1, am_m1, am_v1, am_w2,
                                               Wf, bfin, out);
}

// Round 5
// 685.542 us; speedup vs baseline: 4.0556x; 4.0556x over previous
//
#include <hip/hip_runtime.h>
#include <math.h>

#define DIM   256
#define KNN   16
#define NPTS  2048
#define NB    8
#define TOTPTS (NB * NPTS)   // 16384
#define RSB   528            // act tile row stride bytes (256*2 + 16B pad)

typedef __attribute__((ext_vector_type(8))) short bf16x8;   // 8 bf16 = 4 VGPR (MFMA A/B frag)
typedef __attribute__((ext_vector_type(4))) float f32x4;    // MFMA C/D frag

__device__ __forceinline__ unsigned short f2b(float f) {
    unsigned u = __builtin_bit_cast(unsigned, f);
    return (unsigned short)((u + 0x7fffu + ((u >> 16) & 1u)) >> 16);   // RNE
}
__device__ __forceinline__ unsigned pack2(float a, float b) {
    return (unsigned)f2b(a) | ((unsigned)f2b(b) << 16);
}

// ws layout (bytes)
#define OFF_KNN 0u
#define OFF_Q   (1u << 20)
#define OFF_K   ((1u << 20) + (16u << 20))
#define OFF_V   ((1u << 20) + (32u << 20))
#define OFF_WB  (49u << 20)                 // 7 bf16 matrices: Wq Wk Wv pm_w2 am_w1 am_w2 Wf
#define OFF_PAR (OFF_WB + 7u * 65536u * 2u) // pm_sc, pm_bo, am_sc, am_bo (4 x 256 f32)

// ------------------------------------------------------------------
// Kernel 0: prep — convert weights fp32->bf16, fuse BN params
// ------------------------------------------------------------------
__global__ void prep_kernel(const float* __restrict__ Wq, const float* __restrict__ Wk,
                            const float* __restrict__ Wv, const float* __restrict__ pm_w2,
                            const float* __restrict__ am_w1, const float* __restrict__ am_w2,
                            const float* __restrict__ Wf,
                            const float* __restrict__ pm_g1, const float* __restrict__ pm_b1,
                            const float* __restrict__ pm_m1, const float* __restrict__ pm_v1,
                            const float* __restrict__ am_g1, const float* __restrict__ am_b1,
                            const float* __restrict__ am_m1, const float* __restrict__ am_v1,
                            unsigned short* __restrict__ wb,
                            float* __restrict__ pm_sc, float* __restrict__ pm_bo,
                            float* __restrict__ am_sc, float* __restrict__ am_bo) {
    const int tid = blockIdx.x * 256 + threadIdx.x;
    const float* srcs[7] = {Wq, Wk, Wv, pm_w2, am_w1, am_w2, Wf};
    for (int i = tid; i < 7 * 65536; i += gridDim.x * 256) {
        const int m = i >> 16, o = i & 65535;
        wb[i] = f2b(srcs[m][o]);
    }
    if (tid < 256) {
        float s = pm_g1[tid] * rsqrtf(pm_v1[tid] + 1e-5f);
        pm_sc[tid] = s;
        pm_bo[tid] = pm_b1[tid] - pm_m1[tid] * s;
        s = am_g1[tid] * rsqrtf(am_v1[tid] + 1e-5f);
        am_sc[tid] = s;
        am_bo[tid] = am_b1[tid] - am_m1[tid] * s;
    }
}

// ------------------------------------------------------------------
// Kernel 1: kNN (unchanged from validated fp32 baseline)
// ------------------------------------------------------------------
__global__ __launch_bounds__(256, 4)
void knn_kernel(const float* __restrict__ pos, int* __restrict__ knn_out) {
    const int pt = blockIdx.x;
    const int b  = pt >> 11;
    const int n  = pt & (NPTS - 1);
    const int t  = threadIdx.x;
    const float* __restrict__ posb = pos + (size_t)b * NPTS * 3;

    const float qx = posb[n * 3 + 0], qy = posb[n * 3 + 1], qz = posb[n * 3 + 2];
    const float sqn = __fadd_rn(__fadd_rn(__fmul_rn(qx, qx), __fmul_rn(qy, qy)),
                                __fmul_rn(qz, qz));
    float d[8];
    #pragma unroll
    for (int i = 0; i < 8; ++i) {
        const int m = t + (i << 8);
        const float mx = posb[m * 3 + 0], my = posb[m * 3 + 1], mz = posb[m * 3 + 2];
        const float sqm = __fadd_rn(__fadd_rn(__fmul_rn(mx, mx), __fmul_rn(my, my)),
                                    __fmul_rn(mz, mz));
        const float dot = __fadd_rn(__fadd_rn(__fmul_rn(qx, mx), __fmul_rn(qy, my)),
                                    __fmul_rn(qz, mz));
        d[i] = __fsub_rn(__fadd_rn(sqn, sqm), __fmul_rn(2.0f, dot));
    }

    __shared__ float sd[4];
    __shared__ int   sm[4];
    __shared__ int   swin;
    unsigned mask = 0;

    for (int r = 0; r < KNN; ++r) {
        float bd = 1e30f;
        int   bm = 0x7fffffff;
        #pragma unroll
        for (int i = 0; i < 8; ++i) {
            if (!((mask >> i) & 1u)) {
                const int m = t + (i << 8);
                if (d[i] < bd || (d[i] == bd && m < bm)) { bd = d[i]; bm = m; }
            }
        }
        #pragma unroll
        for (int off = 32; off >= 1; off >>= 1) {
            const float od = __shfl_xor(bd, off);
            const int   om = __shfl_xor(bm, off);
            if (od < bd || (od == bd && om < bm)) { bd = od; bm = om; }
        }
        const int w = t >> 6;
        if ((t & 63) == 0) { sd[w] = bd; sm[w] = bm; }
        __syncthreads();
        if (t == 0) {
            float fd = sd[0]; int fm = sm[0];
            #pragma unroll
            for (int w2 = 1; w2 < 4; ++w2)
                if (sd[w2] < fd || (sd[w2] == fd && sm[w2] < fm)) { fd = sd[w2]; fm = sm[w2]; }
            swin = fm;
            knn_out[(size_t)pt * KNN + r] = fm;
        }
        __syncthreads();
        const int win = swin;
        if ((win & 255) == t) mask |= 1u << (win >> 8);
        __syncthreads();
    }
}

// ------------------------------------------------------------------
// Shared MFMA stage: acc[rt][ct] += act(64xK bf16 LDS) @ Wb^T (bf16 global)
// wave computes 64 rows x 64 cols (cols [cbase, cbase+64))
// ------------------------------------------------------------------
__device__ __forceinline__ void mfma_stage(const unsigned char* __restrict__ act,
                                           const unsigned short* __restrict__ Wb,
                                           int qr, int sub, int cbase,
                                           f32x4 acc[4][4]) {
    #pragma unroll
    for (int kk = 0; kk < 8; ++kk) {
        const int kb = kk * 64 + sub * 16;
        bf16x8 afr[4], bfr[4];
        #pragma unroll
        for (int rt = 0; rt < 4; ++rt)
            afr[rt] = *(const bf16x8*)(act + (rt * 16 + qr) * RSB + kb);
        #pragma unroll
        for (int ct = 0; ct < 4; ++ct)
            bfr[ct] = *(const bf16x8*)(Wb + (size_t)(cbase + ct * 16 + qr) * DIM + kk * 32 + sub * 8);
        #pragma unroll
        for (int rt = 0; rt < 4; ++rt)
            #pragma unroll
            for (int ct = 0; ct < 4; ++ct)
                acc[rt][ct] = __builtin_amdgcn_mfma_f32_16x16x32_bf16(afr[rt], bfr[ct],
                                                                      acc[rt][ct], 0, 0, 0);
    }
}

// ------------------------------------------------------------------
// Kernel 2: q/k/v projections via MFMA. grid = (256 row-blocks, 3 mats)
// ------------------------------------------------------------------
__global__ __launch_bounds__(256, 2)
void qkv_mfma(const float* __restrict__ X, const unsigned short* __restrict__ wb,
              float* __restrict__ Q, float* __restrict__ Kf, float* __restrict__ Vf) {
    __shared__ uint4 act4[64 * RSB / 16];
    unsigned char* act = (unsigned char*)act4;
    const int t = threadIdx.x, lane = t & 63, w = t >> 6;
    const int qr = lane & 15, sub = lane >> 4;
    const int m0 = blockIdx.x * 64;
    const int mat = blockIdx.y;
    const unsigned short* __restrict__ Wb = wb + (size_t)mat * 65536;
    float* __restrict__ O = (mat == 0) ? Q : (mat == 1) ? Kf : Vf;

    // stage X tile (64x256) -> bf16 LDS
    {
        const int r = t >> 2;
        const float* __restrict__ src = X + (size_t)(m0 + r) * DIM;
        #pragma unroll
        for (int j = 0; j < 8; ++j) {
            const int col = (t & 3) * 8 + j * 32;
            const float4 f0 = *(const float4*)(src + col);
            const float4 f1 = *(const float4*)(src + col + 4);
            uint4 u;
            u.x = pack2(f0.x, f0.y); u.y = pack2(f0.z, f0.w);
            u.z = pack2(f1.x, f1.y); u.w = pack2(f1.z, f1.w);
            *(uint4*)(act + r * RSB + col * 2) = u;
        }
    }
    __syncthreads();

    f32x4 acc[4][4];
    #pragma unroll
    for (int rt = 0; rt < 4; ++rt)
        #pragma unroll
        for (int ct = 0; ct < 4; ++ct) acc[rt][ct] = (f32x4)(0.0f);

    mfma_stage(act, Wb, qr, sub, w * 64, acc);

    #pragma unroll
    for (int rt = 0; rt < 4; ++rt)
        #pragma unroll
        for (int ct = 0; ct < 4; ++ct) {
            const int c = w * 64 + ct * 16 + qr;
            #pragma unroll
            for (int reg = 0; reg < 4; ++reg)
                O[(size_t)(m0 + rt * 16 + sub * 4 + reg) * DIM + c] = acc[rt][ct][reg];
        }
}

// ------------------------------------------------------------------
// Kernel 3: fused per-point transformer, MFMA everywhere.
// block = 256 thr = 4 waves = 4 points (64-row M-tile).
// wave w owns cols [64w, 64w+64); pe & attn stay in fp32 VGPRs.
// ------------------------------------------------------------------
__global__ __launch_bounds__(256, 2)
void fused_attn(const float* __restrict__ x, const float* __restrict__ pos,
                const int* __restrict__ knn,
                const float* __restrict__ qf, const float* __restrict__ kf,
                const float* __restrict__ vf,
                const unsigned short* __restrict__ wb,
                const float* __restrict__ pm_w1,
                const float* __restrict__ pm_sc, const float* __restrict__ pm_bo,
                const float* __restrict__ am_sc, const float* __restrict__ am_bo,
                const float* __restrict__ bfin,
                float* __restrict__ out) {
    __shared__ uint4 act4[64 * RSB / 16];     // 33792 B
    __shared__ int   nb_lds[64];
    __shared__ float4 rel_lds[64];
    unsigned char* act = (unsigned char*)act4;

    const int t = threadIdx.x, lane = t & 63, w = t >> 6;
    const int qr = lane & 15, sub = lane >> 4;
    const int pt_base = blockIdx.x << 2;
    const int bbase = pt_base & ~(NPTS - 1);
    const int cbase = w * 64;

    // neighbor idx + rel staging (threads 0..63: one (point, neighbor) each)
    if (t < 64) {
        const int pi = t >> 4;
        const int j = knn[(size_t)(pt_base + pi) * KNN + (t & 15)];
        nb_lds[t] = j;
        const float* __restrict__ pp = pos + (size_t)(pt_base + pi) * 3;
        const float* __restrict__ pj = pos + (size_t)(bbase + j) * 3;
        rel_lds[t] = make_float4(pp[0] - pj[0], pp[1] - pj[1], pp[2] - pj[2], 0.0f);
    }
    __syncthreads();

    // ---- stage 1: pe1 = relu(bn(rel @ pm_w1^T)) -> act LDS (bf16). thread t = col t
    {
        const int c = t;
        const float w0 = pm_w1[c * 3 + 0], w1 = pm_w1[c * 3 + 1], w2 = pm_w1[c * 3 + 2];
        const float sc = pm_sc[c], bo = pm_bo[c];
        for (int r = 0; r < 64; ++r) {
            const float4 rl = rel_lds[r];
            float h = fmaf(rl.z, w2, fmaf(rl.y, w1, rl.x * w0));
            h = fmaxf(fmaf(h, sc, bo), 0.0f);
            *(unsigned short*)(act + r * RSB + c * 2) = f2b(h);
        }
    }
    __syncthreads();

    // ---- stage 2: pe = pe1 @ pm_w2^T (MFMA) -> peacc (fp32, kept to the end)
    f32x4 peacc[4][4];
    #pragma unroll
    for (int rt = 0; rt < 4; ++rt)
        #pragma unroll
        for (int ct = 0; ct < 4; ++ct) peacc[rt][ct] = (f32x4)(0.0f);
    mfma_stage(act, wb + 3u * 65536u, qr, sub, cbase, peacc);
    __syncthreads();   // pe1 reads done

    // hoist this lane's neighbor indices: rows sub*4+reg of each point
    int nbr[4][4];
    #pragma unroll
    for (int rt = 0; rt < 4; ++rt)
        #pragma unroll
        for (int reg = 0; reg < 4; ++reg)
            nbr[rt][reg] = nb_lds[rt * 16 + sub * 4 + reg];

    // ---- stage 3: a0 = q - k_gather + pe -> act LDS (bf16)
    #pragma unroll
    for (int rt = 0; rt < 4; ++rt)
        #pragma unroll
        for (int ct = 0; ct < 4; ++ct) {
            const int c = cbase + ct * 16 + qr;
            const float qv = qf[(size_t)(pt_base + rt) * DIM + c];
            #pragma unroll
            for (int reg = 0; reg < 4; ++reg) {
                const float kv = kf[(size_t)(bbase + nbr[rt][reg]) * DIM + c];
                const float a0 = qv - kv + peacc[rt][ct][reg];
                *(unsigned short*)(act + (rt * 16 + sub * 4 + reg) * RSB + c * 2) = f2b(a0);
            }
        }
    __syncthreads();

    // ---- stage 4: a1 = relu(bn(a0 @ am_w1^T))
    f32x4 acc2[4][4];
    #pragma unroll
    for (int rt = 0; rt < 4; ++rt)
        #pragma unroll
        for (int ct = 0; ct < 4; ++ct) acc2[rt][ct] = (f32x4)(0.0f);
    mfma_stage(act, wb + 4u * 65536u, qr, sub, cbase, acc2);
    __syncthreads();   // a0 reads done
    #pragma unroll
    for (int ct = 0; ct < 4; ++ct) {
        const int c = cbase + ct * 16 + qr;
        const float sc = am_sc[c], bo = am_bo[c];
        #pragma unroll
        for (int rt = 0; rt < 4; ++rt)
            #pragma unroll
            for (int reg = 0; reg < 4; ++reg) {
                const float h = fmaxf(fmaf(acc2[rt][ct][reg], sc, bo), 0.0f);
                *(unsigned short*)(act + (rt * 16 + sub * 4 + reg) * RSB + c * 2) = f2b(h);
            }
    }
    __syncthreads();

    // ---- stage 5: a2 = a1 @ am_w2^T
    #pragma unroll
    for (int rt = 0; rt < 4; ++rt)
        #pragma unroll
        for (int ct = 0; ct < 4; ++ct) acc2[rt][ct] = (f32x4)(0.0f);
    mfma_stage(act, wb + 5u * 65536u, qr, sub, cbase, acc2);

    // ---- stage 6: softmax over the 16 neighbors (rows of each row-tile)
    #pragma unroll
    for (int rt = 0; rt < 4; ++rt)
        #pragma unroll
        for (int ct = 0; ct < 4; ++ct) {
            float m = -1e30f;
            #pragma unroll
            for (int reg = 0; reg < 4; ++reg) {
                acc2[rt][ct][reg] *= 0.0625f;   // / sqrt(256)
                m = fmaxf(m, acc2[rt][ct][reg]);
            }
            m = fmaxf(m, __shfl_xor(m, 16));
            m = fmaxf(m, __shfl_xor(m, 32));
            float s = 0.0f;
            #pragma unroll
            for (int reg = 0; reg < 4; ++reg) {
                const float e = __expf(acc2[rt][ct][reg] - m);
                acc2[rt][ct][reg] = e;
                s += e;
            }
            s += __shfl_xor(s, 16);
            s += __shfl_xor(s, 32);
            const float inv = 1.0f / s;
            #pragma unroll
            for (int reg = 0; reg < 4; ++reg) acc2[rt][ct][reg] *= inv;
        }

    // ---- stage 7: agg[pi][c] = sum_k attn * (v_gather + pe)
    float agg[4][4];
    #pragma unroll
    for (int rt = 0; rt < 4; ++rt)
        #pragma unroll
        for (int ct = 0; ct < 4; ++ct) {
            const int c = cbase + ct * 16 + qr;
            float p = 0.0f;
            #pragma unroll
            for (int reg = 0; reg < 4; ++reg) {
                const float vv = vf[(size_t)(bbase + nbr[rt][reg]) * DIM + c];
                p = fmaf(acc2[rt][ct][reg], vv + peacc[rt][ct][reg], p);
            }
            p += __shfl_xor(p, 16);
            p += __shfl_xor(p, 32);
            agg[rt][ct] = p;
        }
    __syncthreads();   // all act (a1) reads long done; safe to overwrite

    // ---- stage 8: final linear via MFMA on a 16x256 A-tile (rows 0-3 = points)
    {
        unsigned* actw = (unsigned*)act;
        for (int i = t; i < 12 * RSB / 4; i += 256) actw[RSB + i] = 0;  // zero rows 4..15
        if (sub == 0) {
            #pragma unroll
            for (int rt = 0; rt < 4; ++rt)
                #pragma unroll
                for (int ct = 0; ct < 4; ++ct) {
                    const int c = cbase + ct * 16 + qr;
                    *(unsigned short*)(act + rt * RSB + c * 2) = f2b(agg[rt][ct]);
                }
        }
    }
    __syncthreads();

    f32x4 facc[4];
    #pragma unroll
    for (int ct = 0; ct < 4; ++ct) facc[ct] = (f32x4)(0.0f);
    const unsigned short* __restrict__ Wfb = wb + 6u * 65536u;
    #pragma unroll
    for (int kk = 0; kk < 8; ++kk) {
        const int kb = kk * 64 + sub * 16;
        const bf16x8 af = *(const bf16x8*)(act + qr * RSB + kb);
        #pragma unroll
        for (int ct = 0; ct < 4; ++ct) {
            const bf16x8 bfr = *(const bf16x8*)(Wfb + (size_t)(cbase + ct * 16 + qr) * DIM + kk * 32 + sub * 8);
            facc[ct] = __builtin_amdgcn_mfma_f32_16x16x32_bf16(af, bfr, facc[ct], 0, 0, 0);
        }
    }
    if (sub == 0) {
        #pragma unroll
        for (int ct = 0; ct < 4; ++ct) {
            const int c = cbase + ct * 16 + qr;
            #pragma unroll
            for (int reg = 0; reg < 4; ++reg) {
                const size_t row = (size_t)(pt_base + reg) * DIM + c;
                out[row] = facc[ct][reg] + bfin[c] + x[row];
            }
        }
    }
}

// ------------------------------------------------------------------
extern "C" void kernel_launch(void* const* d_in, const int* in_sizes, int n_in,
                              void* d_out, int out_size, void* d_ws, size_t ws_size,
                              hipStream_t stream) {
    const float* x     = (const float*)d_in[0];
    const float* pos   = (const float*)d_in[1];
    const float* Wq    = (const float*)d_in[2];
    const float* Wk    = (const float*)d_in[3];
    const float* Wv    = (const float*)d_in[4];
    const float* pm_w1 = (const float*)d_in[5];
    const float* pm_g1 = (const float*)d_in[6];
    const float* pm_b1 = (const float*)d_in[7];
    const float* pm_m1 = (const float*)d_in[8];
    const float* pm_v1 = (const float*)d_in[9];
    const float* pm_w2 = (const float*)d_in[10];
    const float* am_w1 = (const float*)d_in[11];
    const float* am_g1 = (const float*)d_in[12];
    const float* am_b1 = (const float*)d_in[13];
    const float* am_m1 = (const float*)d_in[14];
    const float* am_v1 = (const float*)d_in[15];
    const float* am_w2 = (const float*)d_in[16];
    const float* Wf    = (const float*)d_in[17];
    const float* bfin  = (const float*)d_in[18];
    float* out = (float*)d_out;

    char* ws = (char*)d_ws;
    int*            knn_idx = (int*)(ws + OFF_KNN);
    float*          qf = (float*)(ws + OFF_Q);
    float*          kf = (float*)(ws + OFF_K);
    float*          vf = (float*)(ws + OFF_V);
    unsigned short* wb = (unsigned short*)(ws + OFF_WB);
    float*          pm_sc = (float*)(ws + OFF_PAR);
    float*          pm_bo = pm_sc + 256;
    float*          am_sc = pm_sc + 512;
    float*          am_bo = pm_sc + 768;

    prep_kernel<<<448, 256, 0, stream>>>(Wq, Wk, Wv, pm_w2, am_w1, am_w2, Wf,
                                         pm_g1, pm_b1, pm_m1, pm_v1,
                                         am_g1, am_b1, am_m1, am_v1,
                                         wb, pm_sc, pm_bo, am_sc, am_bo);
    knn_kernel<<<TOTPTS, 256, 0, stream>>>(pos, knn_idx);
    qkv_mfma<<<dim3(TOTPTS / 64, 3), 256, 0, stream>>>(x, wb, qf, kf, vf);
    fused_attn<<<TOTPTS / 4, 256, 0, stream>>>(x, pos, knn_idx, qf, kf, vf, wb,
                                               pm_w1, pm_sc, pm_bo, am_sc, am_bo,
                                               bfin, out);
}